// Round 4
// baseline (381.636 us; speedup 1.0000x reference)
//
#include <hip/hip_runtime.h>
#include <hip/hip_bf16.h>

#define M_N 100000
#define K_F 512
#define N_F 128
#define N_E 1600000
#define NBLK 391           // ceil(M_N/256)

typedef __attribute__((ext_vector_type(8))) short bf16x8;
typedef __attribute__((ext_vector_type(4))) float f32x4;

__device__ __forceinline__ unsigned short f2bf(float f) {
  unsigned u = __float_as_uint(f);
  u += 0x7FFFu + ((u >> 16) & 1u);      // RNE
  return (unsigned short)(u >> 16);
}

__device__ __forceinline__ unsigned pack_bf2(float a, float b) {
  return (unsigned)f2bf(a) | ((unsigned)f2bf(b) << 16);
}

// ---------- 1) weight: f32 [512][128] -> bf16 transposed [128][512] ----------
__global__ void k_wt(const float* __restrict__ w, unsigned short* __restrict__ wtb) {
  int idx = blockIdx.x * 256 + threadIdx.x;     // 65536 total
  int k = idx >> 7, n = idx & 127;
  wtb[n * K_F + k] = f2bf(w[idx]);              // w[idx] == w[k][n]
}

// ---------- 2) GEMM: zero-LDS, zero-barrier streaming MFMA ----------
// 8 waves/block; wave w owns rows [blk*128 + (w&3)*32, +32) x cols [(w>>2)*64, +64).
// A fragments straight from HBM (f32 -> bf16 in reg), B fragments straight from
// L2 (128KB bf16, resident). Register double-buffer, prefetch distance 1 K-step.
__global__ __launch_bounds__(512, 4) void k_gemm(const float* __restrict__ A,
                       const unsigned short* __restrict__ Bt,   // [128][512] bf16
                       unsigned short* __restrict__ S) {        // [M][128] bf16
  const int tid = threadIdx.x;
  const int lane = tid & 63;
  const int w = tid >> 6;
  const int lr = lane & 15, lq = lane >> 4;
  const int row0 = blockIdx.x * 128 + (w & 3) * 32;
  const int col0 = (w >> 2) * 64;
  if (row0 >= M_N) return;          // 100000 % 32 == 0: waves are all-valid or all-invalid

  const float* a0 = A + (size_t)(row0 + lr) * K_F + lq * 8;
  const float* a1 = a0 + (size_t)16 * K_F;
  const unsigned short* b0 = Bt + (size_t)(col0 + lr) * K_F + lq * 8;

  f32x4 acc[2][4] = {};
  float4 pa[2][2][2];
  bf16x8 pb[2][4];

  // prologue: K-step 0
  pa[0][0][0] = *(const float4*)(a0 + 0);
  pa[0][0][1] = *(const float4*)(a0 + 4);
  pa[0][1][0] = *(const float4*)(a1 + 0);
  pa[0][1][1] = *(const float4*)(a1 + 4);
#pragma unroll
  for (int n = 0; n < 4; n++)
    pb[0][n] = *(const bf16x8*)(b0 + (size_t)n * 16 * K_F);

#pragma unroll
  for (int ks = 0; ks < 16; ks++) {
    const int cur = ks & 1, nxt = cur ^ 1;
    if (ks < 15) {
      const int ko = (ks + 1) * 32;
      pa[nxt][0][0] = *(const float4*)(a0 + ko);
      pa[nxt][0][1] = *(const float4*)(a0 + ko + 4);
      pa[nxt][1][0] = *(const float4*)(a1 + ko);
      pa[nxt][1][1] = *(const float4*)(a1 + ko + 4);
#pragma unroll
      for (int n = 0; n < 4; n++)
        pb[nxt][n] = *(const bf16x8*)(b0 + (size_t)n * 16 * K_F + ko);
    }
#pragma unroll
    for (int m = 0; m < 2; m++) {
      uint4 u;
      u.x = pack_bf2(pa[cur][m][0].x, pa[cur][m][0].y);
      u.y = pack_bf2(pa[cur][m][0].z, pa[cur][m][0].w);
      u.z = pack_bf2(pa[cur][m][1].x, pa[cur][m][1].y);
      u.w = pack_bf2(pa[cur][m][1].z, pa[cur][m][1].w);
      bf16x8 af = *(bf16x8*)&u;
#pragma unroll
      for (int n = 0; n < 4; n++)
        acc[m][n] = __builtin_amdgcn_mfma_f32_16x16x32_bf16(af, pb[cur][n], acc[m][n], 0, 0, 0);
    }
  }

  // epilogue: D layout col=lane&15, row=(lane>>4)*4+j  [measured m89]
#pragma unroll
  for (int m = 0; m < 2; m++)
#pragma unroll
    for (int j = 0; j < 4; j++) {
      int gr = row0 + m * 16 + lq * 4 + j;
#pragma unroll
      for (int n = 0; n < 4; n++)
        S[(size_t)gr * N_F + col0 + n * 16 + lr] = f2bf(acc[m][n][j]);
    }
}

// ---------- 3) histogram of edge_dst ----------
__global__ void k_hist(const int* __restrict__ dst, int* __restrict__ deg) {
  int e = blockIdx.x * 256 + threadIdx.x;
  if (e < N_E) atomicAdd(&deg[dst[e]], 1);
}

// ---------- 4) per-256-block sums ----------
__global__ void k_bsum(const int* __restrict__ deg, int* __restrict__ bsum) {
  __shared__ int sm[256];
  int t = threadIdx.x;
  int i = blockIdx.x * 256 + t;
  sm[t] = (i < M_N) ? deg[i] : 0;
  __syncthreads();
  for (int off = 128; off > 0; off >>= 1) {
    if (t < off) sm[t] += sm[t + off];
    __syncthreads();
  }
  if (t == 0) bsum[blockIdx.x] = sm[0];
}

// ---------- 5) scan the 391 block sums (1 block) ----------
__global__ void k_scanb(const int* __restrict__ bsum, int* __restrict__ bbase,
                        int* __restrict__ rowstart) {
  __shared__ int sm[512];
  int t = threadIdx.x;
  int v = (t < NBLK) ? bsum[t] : 0;
  sm[t] = v;
  __syncthreads();
  for (int off = 1; off < 512; off <<= 1) {
    int cur = sm[t];
    int add = (t >= off) ? sm[t - off] : 0;
    __syncthreads();
    sm[t] = cur + add;
    __syncthreads();
  }
  if (t < NBLK) bbase[t] = sm[t] - v;     // exclusive base per block
  if (t == 511) rowstart[M_N] = sm[511];  // total = N_E
}

// ---------- 6) rowstart + reset fill-cursors (reuses deg buffer) ----------
__global__ void k_rowstart(int* __restrict__ cur /* deg in, cursor out */,
                           const int* __restrict__ bbase, int* __restrict__ rowstart) {
  __shared__ int sm[256];
  int t = threadIdx.x;
  int i = blockIdx.x * 256 + t;
  int d = (i < M_N) ? cur[i] : 0;
  sm[t] = d;
  __syncthreads();
  for (int off = 1; off < 256; off <<= 1) {
    int v = sm[t];
    int add = (t >= off) ? sm[t - off] : 0;
    __syncthreads();
    sm[t] = v + add;
    __syncthreads();
  }
  if (i < M_N) {
    int val = bbase[blockIdx.x] + (sm[t] - d);
    rowstart[i] = val;
    cur[i] = val;
  }
}

// ---------- 7) fill CSR packed (src, w_bits) sorted by dst ----------
__global__ void k_fill(const int* __restrict__ src, const int* __restrict__ dst,
                       const float* __restrict__ w, int* __restrict__ cur,
                       int2* __restrict__ eidx) {
  int e = blockIdx.x * 256 + threadIdx.x;
  if (e < N_E) {
    int d = dst[e];
    int slot = atomicAdd(&cur[d], 1);
    eidx[slot] = make_int2(src[e], __float_as_int(w[e]));
  }
}

// ---------- 8) SpMM gather: one wave per node, 4 edge-groups of 16 lanes ----------
__global__ void k_spmm(const unsigned short* __restrict__ S,
                       const int* __restrict__ rowstart,
                       const int2* __restrict__ eidx,
                       float* __restrict__ out) {
  int wid = (blockIdx.x * 256 + threadIdx.x) >> 6;
  int lane = threadIdx.x & 63;
  if (wid >= M_N) return;
  const int g = lane >> 4;          // edge subgroup 0..3
  const int l = lane & 15;          // 16B chunk within the 256B row
  int s = rowstart[wid], e = rowstart[wid + 1];

  float acc[8] = {0.f, 0.f, 0.f, 0.f, 0.f, 0.f, 0.f, 0.f};

  int i = s + g;
  if (i < e) {
    int2 p = eidx[i];
    for (i += 4; i < e; i += 4) {
      int2 pn = eidx[i];                                   // prefetch next descriptor
      uint4 v = *(const uint4*)(S + (size_t)p.x * N_F + l * 8);
      float wgt = __int_as_float(p.y);
      acc[0] = fmaf(wgt, __uint_as_float(v.x << 16), acc[0]);
      acc[1] = fmaf(wgt, __uint_as_float(v.x & 0xFFFF0000u), acc[1]);
      acc[2] = fmaf(wgt, __uint_as_float(v.y << 16), acc[2]);
      acc[3] = fmaf(wgt, __uint_as_float(v.y & 0xFFFF0000u), acc[3]);
      acc[4] = fmaf(wgt, __uint_as_float(v.z << 16), acc[4]);
      acc[5] = fmaf(wgt, __uint_as_float(v.z & 0xFFFF0000u), acc[5]);
      acc[6] = fmaf(wgt, __uint_as_float(v.w << 16), acc[6]);
      acc[7] = fmaf(wgt, __uint_as_float(v.w & 0xFFFF0000u), acc[7]);
      p = pn;
    }
    uint4 v = *(const uint4*)(S + (size_t)p.x * N_F + l * 8);
    float wgt = __int_as_float(p.y);
    acc[0] = fmaf(wgt, __uint_as_float(v.x << 16), acc[0]);
    acc[1] = fmaf(wgt, __uint_as_float(v.x & 0xFFFF0000u), acc[1]);
    acc[2] = fmaf(wgt, __uint_as_float(v.y << 16), acc[2]);
    acc[3] = fmaf(wgt, __uint_as_float(v.y & 0xFFFF0000u), acc[3]);
    acc[4] = fmaf(wgt, __uint_as_float(v.z << 16), acc[4]);
    acc[5] = fmaf(wgt, __uint_as_float(v.z & 0xFFFF0000u), acc[5]);
    acc[6] = fmaf(wgt, __uint_as_float(v.w << 16), acc[6]);
    acc[7] = fmaf(wgt, __uint_as_float(v.w & 0xFFFF0000u), acc[7]);
  }

  // reduce across the 4 groups (lane bits 4,5) + fused ReLU
#pragma unroll
  for (int j = 0; j < 8; j++) {
    acc[j] += __shfl_xor(acc[j], 16, 64);
    acc[j] += __shfl_xor(acc[j], 32, 64);
    acc[j] = fmaxf(acc[j], 0.f);
  }

  // coalesced 512B store from 32 lanes (groups 0,1)
  if (g < 2) {
    float4 r = make_float4(acc[g * 4 + 0], acc[g * 4 + 1], acc[g * 4 + 2], acc[g * 4 + 3]);
    *(float4*)(out + (size_t)wid * N_F + l * 8 + g * 4) = r;
  }
}

extern "C" void kernel_launch(void* const* d_in, const int* in_sizes, int n_in,
                              void* d_out, int out_size, void* d_ws, size_t ws_size,
                              hipStream_t stream) {
  const float* features = (const float*)d_in[0];
  const float* weight   = (const float*)d_in[1];
  const int* edge_src   = (const int*)d_in[2];
  const int* edge_dst   = (const int*)d_in[3];
  const float* edge_w   = (const float*)d_in[4];
  float* out = (float*)d_out;

  // workspace layout (256B-aligned chunks)
  char* ws = (char*)d_ws;
  size_t off = 0;
  unsigned short* support = (unsigned short*)(ws + off); off += (size_t)M_N * N_F * 2;        // 25.6MB
  unsigned short* wtb     = (unsigned short*)(ws + off); off += (size_t)N_F * K_F * 2;        // 128KB
  int* cursor   = (int*)(ws + off); off += ((size_t)M_N * 4 + 255) / 256 * 256;               // deg/cursor
  int* rowstart = (int*)(ws + off); off += ((size_t)(M_N + 1) * 4 + 255) / 256 * 256;
  int* bsum     = (int*)(ws + off); off += 2048;
  int* bbase    = (int*)(ws + off); off += 2048;
  int2* eidx    = (int2*)(ws + off); off += (size_t)N_E * 8;                                  // 12.8MB

  k_wt<<<256, 256, 0, stream>>>(weight, wtb);
  k_gemm<<<(M_N + 127) / 128, 512, 0, stream>>>(features, wtb, support);
  (void)hipMemsetAsync(cursor, 0, (size_t)M_N * 4, stream);
  k_hist<<<(N_E + 255) / 256, 256, 0, stream>>>(edge_dst, cursor);
  k_bsum<<<NBLK, 256, 0, stream>>>(cursor, bsum);
  k_scanb<<<1, 512, 0, stream>>>(bsum, bbase, rowstart);
  k_rowstart<<<NBLK, 256, 0, stream>>>(cursor, bbase, rowstart);
  k_fill<<<(N_E + 255) / 256, 256, 0, stream>>>(edge_src, edge_dst, edge_w, cursor, eidx);
  k_spmm<<<(M_N * 64 + 255) / 256, 256, 0, stream>>>(support, rowstart, eidx, out);
}

// Round 5
// 345.094 us; speedup vs baseline: 1.1059x; 1.1059x over previous
//
#include <hip/hip_runtime.h>
#include <hip/hip_bf16.h>

#define M_N 100000
#define K_F 512
#define N_F 128
#define N_E 1600000
#define NBLK 391           // ceil(M_N/256)

typedef __attribute__((ext_vector_type(8))) short bf16x8;
typedef __attribute__((ext_vector_type(4))) float f32x4;

__device__ __forceinline__ unsigned short f2bf(float f) {
  unsigned u = __float_as_uint(f);
  u += 0x7FFFu + ((u >> 16) & 1u);      // RNE
  return (unsigned short)(u >> 16);
}

__device__ __forceinline__ unsigned pkbf(float a, float b) {
  __hip_bfloat162 h = __float22bfloat162_rn(make_float2(a, b));
  return *(unsigned*)&h;                // v_cvt_pk_bf16_f32
}

// ---------- 1) weight: f32 [512][128] -> bf16 transposed [128][512] ----------
__global__ void k_wt(const float* __restrict__ w, unsigned short* __restrict__ wtb) {
  int idx = blockIdx.x * 256 + threadIdx.x;     // 65536 total
  int k = idx >> 7, n = idx & 127;
  wtb[n * K_F + k] = f2bf(w[idx]);              // w[idx] == w[k][n]
}

// ---------- 2) GEMM: global_load_lds double-buffered, A f32 in LDS ----------
// Block 256 thr / 4 waves, tile 128 rows x full N=128. Wave w: rows [w*32,+32).
// A staged f32 via global_load_lds (fire-and-forget, 32KB/tile in flight);
// 16B-chunk XOR swizzle (c ^= row&7) applied on global SOURCE + ds_read (T2/m173).
// B read per K-tile straight from L2 into regs (128KB matrix, resident).
__global__ __launch_bounds__(256, 2) void k_gemm(const float* __restrict__ A,
                       const unsigned short* __restrict__ Bt,   // [128][512] bf16
                       unsigned short* __restrict__ S) {        // [M][128] bf16
  __shared__ __align__(16) float As[2][128 * 64];               // 64KB total
  const int tid = threadIdx.x;
  const int lane = tid & 63;
  const int wv = tid >> 6;
  const int lr = lane & 15, lq = lane >> 4;
  const int bm0 = blockIdx.x * 128;
  const int wrow = wv * 32;

  const unsigned short* bbase = Bt + (size_t)lr * K_F + lq * 8;

  f32x4 acc[2][8] = {};

  // prologue: stage tile 0
#pragma unroll
  for (int i = 0; i < 8; i++) {
    int idx = i * 256 + tid;
    int r = idx >> 4, c = idx & 15;
    int gr = bm0 + r; if (gr > M_N - 1) gr = M_N - 1;
    const float* src = A + (size_t)gr * K_F + 0 + (c ^ (r & 7)) * 4;
    __builtin_amdgcn_global_load_lds(
        (const __attribute__((address_space(1))) void*)src,
        (__attribute__((address_space(3))) void*)&As[0][(i * 256 + wv * 64) * 4],
        16, 0, 0);
  }
  __syncthreads();

#pragma unroll
  for (int t = 0; t < 8; t++) {
    const int cur = t & 1;
    const int k0 = t * 64;

    // B fragments for this K-tile (before STAGE: their wait won't drain it)
    bf16x8 pb[8][2];
#pragma unroll
    for (int n = 0; n < 8; n++)
#pragma unroll
      for (int ks = 0; ks < 2; ks++)
        pb[n][ks] = *(const bf16x8*)(bbase + (size_t)n * 16 * K_F + k0 + ks * 32);

    // stage tile t+1 (fire-and-forget)
    if (t < 7) {
#pragma unroll
      for (int i = 0; i < 8; i++) {
        int idx = i * 256 + tid;
        int r = idx >> 4, c = idx & 15;
        int gr = bm0 + r; if (gr > M_N - 1) gr = M_N - 1;
        const float* src = A + (size_t)gr * K_F + (k0 + 64) + (c ^ (r & 7)) * 4;
        __builtin_amdgcn_global_load_lds(
            (const __attribute__((address_space(1))) void*)src,
            (__attribute__((address_space(3))) void*)&As[cur ^ 1][(i * 256 + wv * 64) * 4],
            16, 0, 0);
      }
    }

    // compute on buf[cur]
#pragma unroll
    for (int ks = 0; ks < 2; ks++)
#pragma unroll
      for (int m = 0; m < 2; m++) {
        int R = wrow + m * 16 + lr;
        int cb = ks * 8 + lq * 2;           // 16B-chunk index (pre-swizzle)
        int sw = R & 7;
        f32x4 f0 = *(const f32x4*)&As[cur][(R * 16 + (cb ^ sw)) * 4];
        f32x4 f1 = *(const f32x4*)&As[cur][(R * 16 + ((cb + 1) ^ sw)) * 4];
        uint4 u;
        u.x = pkbf(f0[0], f0[1]);
        u.y = pkbf(f0[2], f0[3]);
        u.z = pkbf(f1[0], f1[1]);
        u.w = pkbf(f1[2], f1[3]);
        bf16x8 af = *(bf16x8*)&u;
#pragma unroll
        for (int n = 0; n < 8; n++)
          acc[m][n] = __builtin_amdgcn_mfma_f32_16x16x32_bf16(af, pb[n][ks], acc[m][n], 0, 0, 0);
      }
    __syncthreads();
  }

  // epilogue: D layout col=lane&15, row=(lane>>4)*4+j  [measured m89]
#pragma unroll
  for (int m = 0; m < 2; m++)
#pragma unroll
    for (int j = 0; j < 4; j++) {
      int gr = bm0 + wrow + m * 16 + lq * 4 + j;
      if (gr < M_N) {
#pragma unroll
        for (int n = 0; n < 8; n++)
          S[(size_t)gr * N_F + n * 16 + lr] = f2bf(acc[m][n][j]);
      }
    }
}

// ---------- 3) histogram of edge_dst ----------
__global__ void k_hist(const int* __restrict__ dst, int* __restrict__ deg) {
  int e = blockIdx.x * 256 + threadIdx.x;
  if (e < N_E) atomicAdd(&deg[dst[e]], 1);
}

// ---------- 4) per-256-block sums ----------
__global__ void k_bsum(const int* __restrict__ deg, int* __restrict__ bsum) {
  __shared__ int sm[256];
  int t = threadIdx.x;
  int i = blockIdx.x * 256 + t;
  sm[t] = (i < M_N) ? deg[i] : 0;
  __syncthreads();
  for (int off = 128; off > 0; off >>= 1) {
    if (t < off) sm[t] += sm[t + off];
    __syncthreads();
  }
  if (t == 0) bsum[blockIdx.x] = sm[0];
}

// ---------- 5) scan the 391 block sums (1 block) ----------
__global__ void k_scanb(const int* __restrict__ bsum, int* __restrict__ bbase,
                        int* __restrict__ rowstart) {
  __shared__ int sm[512];
  int t = threadIdx.x;
  int v = (t < NBLK) ? bsum[t] : 0;
  sm[t] = v;
  __syncthreads();
  for (int off = 1; off < 512; off <<= 1) {
    int cur = sm[t];
    int add = (t >= off) ? sm[t - off] : 0;
    __syncthreads();
    sm[t] = cur + add;
    __syncthreads();
  }
  if (t < NBLK) bbase[t] = sm[t] - v;     // exclusive base per block
  if (t == 511) rowstart[M_N] = sm[511];  // total = N_E
}

// ---------- 6) rowstart + reset fill-cursors (reuses deg buffer) ----------
__global__ void k_rowstart(int* __restrict__ cur /* deg in, cursor out */,
                           const int* __restrict__ bbase, int* __restrict__ rowstart) {
  __shared__ int sm[256];
  int t = threadIdx.x;
  int i = blockIdx.x * 256 + t;
  int d = (i < M_N) ? cur[i] : 0;
  sm[t] = d;
  __syncthreads();
  for (int off = 1; off < 256; off <<= 1) {
    int v = sm[t];
    int add = (t >= off) ? sm[t - off] : 0;
    __syncthreads();
    sm[t] = v + add;
    __syncthreads();
  }
  if (i < M_N) {
    int val = bbase[blockIdx.x] + (sm[t] - d);
    rowstart[i] = val;
    cur[i] = val;
  }
}

// ---------- 7) fill CSR packed (src, w_bits) sorted by dst ----------
__global__ void k_fill(const int* __restrict__ src, const int* __restrict__ dst,
                       const float* __restrict__ w, int* __restrict__ cur,
                       int2* __restrict__ eidx) {
  int e = blockIdx.x * 256 + threadIdx.x;
  if (e < N_E) {
    int d = dst[e];
    int slot = atomicAdd(&cur[d], 1);
    eidx[slot] = make_int2(src[e], __float_as_int(w[e]));
  }
}

// ---------- 8) SpMM gather: one wave per node, 4 edge-groups of 16 lanes ----------
__global__ void k_spmm(const unsigned short* __restrict__ S,
                       const int* __restrict__ rowstart,
                       const int2* __restrict__ eidx,
                       float* __restrict__ out) {
  int wid = (blockIdx.x * 256 + threadIdx.x) >> 6;
  int lane = threadIdx.x & 63;
  if (wid >= M_N) return;
  const int g = lane >> 4;          // edge subgroup 0..3
  const int l = lane & 15;          // 16B chunk within the 256B row
  int s = rowstart[wid], e = rowstart[wid + 1];

  float acc[8] = {0.f, 0.f, 0.f, 0.f, 0.f, 0.f, 0.f, 0.f};

  int i = s + g;
  if (i < e) {
    int2 p = eidx[i];
    for (i += 4; i < e; i += 4) {
      int2 pn = eidx[i];                                   // prefetch next descriptor
      uint4 v = *(const uint4*)(S + (size_t)p.x * N_F + l * 8);
      float wgt = __int_as_float(p.y);
      acc[0] = fmaf(wgt, __uint_as_float(v.x << 16), acc[0]);
      acc[1] = fmaf(wgt, __uint_as_float(v.x & 0xFFFF0000u), acc[1]);
      acc[2] = fmaf(wgt, __uint_as_float(v.y << 16), acc[2]);
      acc[3] = fmaf(wgt, __uint_as_float(v.y & 0xFFFF0000u), acc[3]);
      acc[4] = fmaf(wgt, __uint_as_float(v.z << 16), acc[4]);
      acc[5] = fmaf(wgt, __uint_as_float(v.z & 0xFFFF0000u), acc[5]);
      acc[6] = fmaf(wgt, __uint_as_float(v.w << 16), acc[6]);
      acc[7] = fmaf(wgt, __uint_as_float(v.w & 0xFFFF0000u), acc[7]);
      p = pn;
    }
    uint4 v = *(const uint4*)(S + (size_t)p.x * N_F + l * 8);
    float wgt = __int_as_float(p.y);
    acc[0] = fmaf(wgt, __uint_as_float(v.x << 16), acc[0]);
    acc[1] = fmaf(wgt, __uint_as_float(v.x & 0xFFFF0000u), acc[1]);
    acc[2] = fmaf(wgt, __uint_as_float(v.y << 16), acc[2]);
    acc[3] = fmaf(wgt, __uint_as_float(v.y & 0xFFFF0000u), acc[3]);
    acc[4] = fmaf(wgt, __uint_as_float(v.z << 16), acc[4]);
    acc[5] = fmaf(wgt, __uint_as_float(v.z & 0xFFFF0000u), acc[5]);
    acc[6] = fmaf(wgt, __uint_as_float(v.w << 16), acc[6]);
    acc[7] = fmaf(wgt, __uint_as_float(v.w & 0xFFFF0000u), acc[7]);
  }

  // reduce across the 4 groups (lane bits 4,5) + fused ReLU
#pragma unroll
  for (int j = 0; j < 8; j++) {
    acc[j] += __shfl_xor(acc[j], 16, 64);
    acc[j] += __shfl_xor(acc[j], 32, 64);
    acc[j] = fmaxf(acc[j], 0.f);
  }

  // coalesced 512B store from 32 lanes (groups 0,1)
  if (g < 2) {
    float4 r = make_float4(acc[g * 4 + 0], acc[g * 4 + 1], acc[g * 4 + 2], acc[g * 4 + 3]);
    *(float4*)(out + (size_t)wid * N_F + l * 8 + g * 4) = r;
  }
}

extern "C" void kernel_launch(void* const* d_in, const int* in_sizes, int n_in,
                              void* d_out, int out_size, void* d_ws, size_t ws_size,
                              hipStream_t stream) {
  const float* features = (const float*)d_in[0];
  const float* weight   = (const float*)d_in[1];
  const int* edge_src   = (const int*)d_in[2];
  const int* edge_dst   = (const int*)d_in[3];
  const float* edge_w   = (const float*)d_in[4];
  float* out = (float*)d_out;

  // workspace layout (256B-aligned chunks)
  char* ws = (char*)d_ws;
  size_t off = 0;
  unsigned short* support = (unsigned short*)(ws + off); off += (size_t)M_N * N_F * 2;        // 25.6MB
  unsigned short* wtb     = (unsigned short*)(ws + off); off += (size_t)N_F * K_F * 2;        // 128KB
  int* cursor   = (int*)(ws + off); off += ((size_t)M_N * 4 + 255) / 256 * 256;               // deg/cursor
  int* rowstart = (int*)(ws + off); off += ((size_t)(M_N + 1) * 4 + 255) / 256 * 256;
  int* bsum     = (int*)(ws + off); off += 2048;
  int* bbase    = (int*)(ws + off); off += 2048;
  int2* eidx    = (int2*)(ws + off); off += (size_t)N_E * 8;                                  // 12.8MB

  k_wt<<<256, 256, 0, stream>>>(weight, wtb);
  k_gemm<<<(M_N + 127) / 128, 256, 0, stream>>>(features, wtb, support);
  (void)hipMemsetAsync(cursor, 0, (size_t)M_N * 4, stream);
  k_hist<<<(N_E + 255) / 256, 256, 0, stream>>>(edge_dst, cursor);
  k_bsum<<<NBLK, 256, 0, stream>>>(cursor, bsum);
  k_scanb<<<1, 512, 0, stream>>>(bsum, bbase, rowstart);
  k_rowstart<<<NBLK, 256, 0, stream>>>(cursor, bbase, rowstart);
  k_fill<<<(N_E + 255) / 256, 256, 0, stream>>>(edge_src, edge_dst, edge_w, cursor, eidx);
  k_spmm<<<(M_N * 64 + 255) / 256, 256, 0, stream>>>(support, rowstart, eidx, out);
}